// Round 3
// baseline (12082.931 us; speedup 1.0000x reference)
//
#include <hip/hip_runtime.h>
#include <hip/hip_cooperative_groups.h>

namespace cg = cooperative_groups;

// KMeans++ init on MI355X. B=32, N=16384, D=64, K=64.
// data: (B,N,D) fp32; first_idx: (B,) int32. Output centers: (B,K,D) fp32.
//
// Primary path: ONE persistent cooperative kernel, grid.sync between the 63
// sequential steps. min_d lives in LDS (not registers -> low VGPR count so
// 4 blocks/CU co-residency holds). Grid size chosen at launch time from
// hipOccupancyMaxActiveBlocksPerMultiprocessor (deterministic, capture-safe).
// Fallback path (if cooperative launch is rejected): the round-1 multi-launch
// kernels, proven correct at 1827 us.
//
// Coalesced mapping: lane = sub*16 + d4; lane handles float4 #d4 of point
// (pass*4 + sub) -> one wave64 dwordx4 = contiguous 1 KB. Per-point distance
// reduced across the 16-lane sub-group with 4 shfl_xor (DPP adds).

#define B_   32
#define N_   16384
#define D_   64
#define K_   64
#define T_   256
#define WPB  (T_ / 64)     // 4 waves per block
#define MAXCHUNK 1024      // points/block at gshift=4 (512 blocks)

// numpy argmax semantics: on equal value keep the smaller index.
__device__ __forceinline__ void amax_comb(float& v, int& i, float v2, int i2) {
    if (v2 > v || (v2 == v && i2 < i)) { v = v2; i = i2; }
}

// ------------------------- cooperative primary path -------------------------

__global__ __launch_bounds__(T_, 4) void kmpp_coop(
    const float* __restrict__ data, const int* __restrict__ first_idx,
    float* __restrict__ pval, int* __restrict__ pidx,
    float* __restrict__ centers, int gshift)
{
    cg::grid_group grid = cg::this_grid();
    const int gpb   = 1 << gshift;        // blocks per batch (16 or 32)
    const int chunk = N_ >> gshift;       // points per block (1024 or 512)
    const int npass = chunk >> 4;         // passes per wave (4 points each)
    const int b = blockIdx.x >> gshift;
    const int g = blockIdx.x & (gpb - 1);
    const int wave = threadIdx.x >> 6;
    const int lane = threadIdx.x & 63;
    const int sub  = lane >> 4;           // point-in-pass 0..3
    const int d4   = lane & 15;           // float4 index within the D=64 row

    const float* __restrict__ bdata = data + (size_t)b * N_ * D_;
    const int ppw = chunk >> 2;           // points per wave
    const int lbase = wave * ppw;         // this wave's local point base

    __shared__ float  md[MAXCHUNK];       // running min squared distance
    __shared__ float4 csh[D_ / 4];
    __shared__ float  red_v[WPB];
    __shared__ int    red_i[WPB];
    __shared__ int    s_ci;

    for (int i = threadIdx.x; i < chunk; i += T_) md[i] = 3.4e38f;

    for (int k = 0; k < K_; ++k) {
        // ---- this step's center index ----
        if (k == 0) {
            if (threadIdx.x == 0) s_ci = first_idx[b];
        } else if (wave == 0) {
            float v = -1.f; int i = 0x7fffffff;
            if (lane < gpb) {
                const int pin = (k - 1) & 1;
                v = pval[(b * 2 + pin) * gpb + lane];
                i = pidx[(b * 2 + pin) * gpb + lane];
            }
            #pragma unroll
            for (int m = 1; m < 64; m <<= 1) {
                float v2 = __shfl_xor(v, m, 64);
                int   i2 = __shfl_xor(i, m, 64);
                amax_comb(v, i, v2, i2);
            }
            if (lane == 0) s_ci = i;
        }
        __syncthreads();
        const int ci = s_ci;

        // ---- stage center row; one block per batch writes the output ----
        if (threadIdx.x < D_ / 4)
            csh[threadIdx.x] = ((const float4*)(bdata + (size_t)ci * D_))[threadIdx.x];
        __syncthreads();
        if (g == 0 && threadIdx.x < D_ / 4)
            ((float4*)(centers + ((size_t)b * K_ + k) * D_))[threadIdx.x] = csh[threadIdx.x];
        if (k == K_ - 1) break;           // uniform across the whole grid

        // ---- min_d update + local argmax ----
        const float4 c = csh[d4];
        float bv = -1.f; int bi = 0x7fffffff;
        #pragma unroll 4
        for (int pass = 0; pass < npass; ++pass) {
            const int lp = lbase + pass * 4 + sub;           // local point
            const int p  = g * chunk + lp;                   // point in batch
            float4 x = ((const float4*)(bdata + (size_t)p * D_))[d4];
            float dx = x.x - c.x, dy = x.y - c.y, dz = x.z - c.z, dw = x.w - c.w;
            float s = fmaf(dx, dx, fmaf(dy, dy, fmaf(dz, dz, dw * dw)));
            s += __shfl_xor(s, 1, 64);
            s += __shfl_xor(s, 2, 64);
            s += __shfl_xor(s, 4, 64);
            s += __shfl_xor(s, 8, 64);    // all 16 lanes now hold d(p)
            float nv = fminf(md[lp], s);  // 16-lane broadcast read: free
            if (d4 == 0) md[lp] = nv;
            amax_comb(bv, bi, nv, p);     // duplicates across sub: harmless
        }
        #pragma unroll
        for (int m = 1; m < 64; m <<= 1) {
            float v2 = __shfl_xor(bv, m, 64);
            int   i2 = __shfl_xor(bi, m, 64);
            amax_comb(bv, bi, v2, i2);
        }
        if (lane == 0) { red_v[wave] = bv; red_i[wave] = bi; }
        __syncthreads();
        if (threadIdx.x == 0) {
            #pragma unroll
            for (int w = 1; w < WPB; ++w) amax_comb(bv, bi, red_v[w], red_i[w]);
            pval[(b * 2 + (k & 1)) * gpb + g] = bv;
            pidx[(b * 2 + (k & 1)) * gpb + g] = bi;
        }
        __threadfence();                  // cross-XCD visibility of partials
        grid.sync();
    }
}

// ------------------- round-1 multi-launch fallback path ---------------------
// Proven correct (absmax 0). Used only if the cooperative launch is rejected.

#define FG   16            // blocks per batch
#define FPPT 4             // points per thread
#define FCHUNK (N_ / FG)   // 1024 points per block

__device__ __forceinline__ void fb_block_argmax_store(
    float v, int i, int b, int g, int parity,
    float* __restrict__ pval, int* __restrict__ pidx,
    float* red_v, int* red_i)
{
    #pragma unroll
    for (int off = 32; off > 0; off >>= 1) {
        float v2 = __shfl_down(v, off, 64);
        int   i2 = __shfl_down(i, off, 64);
        amax_comb(v, i, v2, i2);
    }
    int lane = threadIdx.x & 63;
    int wave = threadIdx.x >> 6;
    if (lane == 0) { red_v[wave] = v; red_i[wave] = i; }
    __syncthreads();
    if (threadIdx.x == 0) {
        #pragma unroll
        for (int w = 1; w < T_ / 64; ++w) amax_comb(v, i, red_v[w], red_i[w]);
        pval[(b * 2 + parity) * FG + g] = v;
        pidx[(b * 2 + parity) * FG + g] = i;
    }
}

__device__ __forceinline__ float fb_dist2(const float4* __restrict__ row,
                                          const float4* csh)
{
    float ax = 0.f, ay = 0.f, az = 0.f, aw = 0.f;
    #pragma unroll
    for (int j = 0; j < D_ / 4; ++j) {
        float4 x = row[j];
        float4 c = csh[j];
        float dx = x.x - c.x, dy = x.y - c.y, dz = x.z - c.z, dw = x.w - c.w;
        ax = fmaf(dx, dx, ax);
        ay = fmaf(dy, dy, ay);
        az = fmaf(dz, dz, az);
        aw = fmaf(dw, dw, aw);
    }
    return (ax + ay) + (az + aw);
}

__global__ __launch_bounds__(T_) void kmpp_init(
    const float* __restrict__ data, const int* __restrict__ first_idx,
    float* __restrict__ min_d, float* __restrict__ pval, int* __restrict__ pidx,
    float* __restrict__ centers)
{
    const int blk = blockIdx.x;
    const int b = blk / FG, g = blk % FG;
    __shared__ float4 csh[D_ / 4];
    __shared__ float red_v[T_ / 64];
    __shared__ int   red_i[T_ / 64];

    const int ci = first_idx[b];
    const float4* crow = (const float4*)(data + ((size_t)b * N_ + ci) * D_);
    if (threadIdx.x < D_ / 4) csh[threadIdx.x] = crow[threadIdx.x];
    __syncthreads();
    if (g == 0 && threadIdx.x < D_ / 4)
        ((float4*)(centers + (size_t)b * K_ * D_))[threadIdx.x] = csh[threadIdx.x];

    float best_v = -1.f; int best_i = 0;
    for (int m = 0; m < FPPT; ++m) {
        const int p = g * FCHUNK + m * T_ + threadIdx.x;
        const float4* row = (const float4*)(data + ((size_t)b * N_ + p) * D_);
        float d = fb_dist2(row, csh);
        min_d[(size_t)b * N_ + p] = d;
        amax_comb(best_v, best_i, d, p);
    }
    fb_block_argmax_store(best_v, best_i, b, g, 0, pval, pidx, red_v, red_i);
}

__global__ __launch_bounds__(T_) void kmpp_step(
    const float* __restrict__ data, float* __restrict__ min_d,
    float* __restrict__ pval, int* __restrict__ pidx,
    float* __restrict__ centers, int k)
{
    const int blk = blockIdx.x;
    const int b = blk / FG, g = blk % FG;
    const int pin = (k - 1) & 1, pout = k & 1;
    __shared__ float4 csh[D_ / 4];
    __shared__ float red_v[T_ / 64];
    __shared__ int   red_i[T_ / 64];
    __shared__ int   sidx;

    if (threadIdx.x == 0) {
        float v = pval[(b * 2 + pin) * FG];
        int   i = pidx[(b * 2 + pin) * FG];
        for (int gg = 1; gg < FG; ++gg)
            amax_comb(v, i, pval[(b * 2 + pin) * FG + gg], pidx[(b * 2 + pin) * FG + gg]);
        sidx = i;
    }
    __syncthreads();
    const int ci = sidx;
    const float4* crow = (const float4*)(data + ((size_t)b * N_ + ci) * D_);
    if (threadIdx.x < D_ / 4) csh[threadIdx.x] = crow[threadIdx.x];
    __syncthreads();
    if (g == 0 && threadIdx.x < D_ / 4)
        ((float4*)(centers + ((size_t)b * K_ + k) * D_))[threadIdx.x] = csh[threadIdx.x];

    if (k == K_ - 1) return;

    float best_v = -1.f; int best_i = 0;
    for (int m = 0; m < FPPT; ++m) {
        const int p = g * FCHUNK + m * T_ + threadIdx.x;
        const float4* row = (const float4*)(data + ((size_t)b * N_ + p) * D_);
        float d = fb_dist2(row, csh);
        const size_t off = (size_t)b * N_ + p;
        float nv = fminf(min_d[off], d);
        min_d[off] = nv;
        amax_comb(best_v, best_i, nv, p);
    }
    fb_block_argmax_store(best_v, best_i, b, g, pout, pval, pidx, red_v, red_i);
}

// ---------------------------------------------------------------------------

extern "C" void kernel_launch(void* const* d_in, const int* in_sizes, int n_in,
                              void* d_out, int out_size, void* d_ws, size_t ws_size,
                              hipStream_t stream)
{
    const float* data      = (const float*)d_in[0];
    const int*   first_idx = (const int*)d_in[1];
    float*       centers   = (float*)d_out;

    // ws layout: min_d[B*N] (fallback only) | pval[B*2*32] | pidx[B*2*32]
    float* min_d = (float*)d_ws;
    float* pval  = min_d + (size_t)B_ * N_;
    int*   pidx  = (int*)(pval + B_ * 2 * 32);

    // Capture-safe occupancy query (no stream ops, deterministic every call).
    int occ = 0;
    hipError_t qerr = hipOccupancyMaxActiveBlocksPerMultiprocessor(
        &occ, kmpp_coop, T_, 0);
    int gshift = 0;
    if (qerr == hipSuccess) {
        if (occ >= 4)      gshift = 5;   // 1024 blocks = 4/CU
        else if (occ >= 2) gshift = 4;   // 512 blocks  = 2/CU
    }

    if (gshift) {
        void* args[] = { (void*)&data, (void*)&first_idx,
                         (void*)&pval, (void*)&pidx, (void*)&centers,
                         (void*)&gshift };
        hipError_t err = hipLaunchCooperativeKernel(
            (const void*)kmpp_coop, dim3(B_ << gshift), dim3(T_), args, 0, stream);
        if (err == hipSuccess) return;
        (void)hipGetLastError();   // clear sticky error, fall through
    }

    // Fallback: proven multi-launch path.
    dim3 grid(B_ * FG), block(T_);
    hipLaunchKernelGGL(kmpp_init, grid, block, 0, stream,
                       data, first_idx, min_d, pval, pidx, centers);
    for (int k = 1; k < K_; ++k) {
        hipLaunchKernelGGL(kmpp_step, grid, block, 0, stream,
                           data, min_d, pval, pidx, centers, k);
    }
}

// Round 4
// 1492.532 us; speedup vs baseline: 8.0956x; 8.0956x over previous
//
#include <hip/hip_runtime.h>

// KMeans++ init on MI355X. B=32, N=16384, D=64, K=64.
// data: (B,N,D) fp32; first_idx: (B,) int32. Output centers: (B,K,D) fp32.
//
// Round-4 design: ONE persistent kernel (cooperative launch for co-residency
// only -- NO grid.sync, NO threadfence). Cross-block communication per step is
// exactly 8 bytes per block: a write-once packed (dist,idx) slot per
// (step, batch, block), accessed with RELAXED agent-scope atomics. Relaxed is
// sufficient because the slot word itself carries all transferred data:
// `data` is immutable, min_d is block-private LDS. Avoiding acquire/release
// fences keeps read-only data lines live in L2/L3 across steps (the round-3
// grid.sync L2-invalidate was the 12 ms disaster).
//
// Packing: (float_bits(val) << 32) | (uint32)~idx. val >= 0 so float-bit order
// == integer order; ties pick larger ~idx == smaller idx (numpy argmax).
// Low word ~idx is never 0 (idx < 16384), so slot==0 means "not written".

#define B_   32
#define N_   16384
#define D_   64
#define K_   64
#define T_   256
#define WPB  4
#define SLOTS_PER_K (B_ * 32)

typedef unsigned long long u64;

// numpy argmax semantics: on equal value keep the smaller index.
__device__ __forceinline__ void amax_comb(float& v, int& i, float v2, int i2) {
    if (v2 > v || (v2 == v && i2 < i)) { v = v2; i = i2; }
}

__global__ void kmpp_zero_slots(u64* __restrict__ slots, int n) {
    int i = blockIdx.x * blockDim.x + threadIdx.x;
    if (i < n) slots[i] = 0ULL;
}

// ------------------------- persistent primary path --------------------------

template <int GSHIFT>
__global__ __launch_bounds__(T_, 4) void kmpp_coop(
    const float* __restrict__ data, const int* __restrict__ first_idx,
    u64* __restrict__ slots, float* __restrict__ centers)
{
    constexpr int gpb   = 1 << GSHIFT;   // blocks per batch
    constexpr int chunk = N_ >> GSHIFT;  // points per block
    constexpr int npass = chunk / 16;    // 4 points per pass per wave
    constexpr int ppw   = chunk / 4;     // points per wave

    const int b    = blockIdx.x >> GSHIFT;
    const int g    = blockIdx.x & (gpb - 1);
    const int wave = threadIdx.x >> 6;
    const int lane = threadIdx.x & 63;
    const int sub  = lane >> 4;          // point-in-pass 0..3
    const int d4   = lane & 15;          // float4 index in the 64-elem row

    const float* __restrict__ bdata = data + (size_t)b * N_ * D_;
    const float4* __restrict__ rowp = (const float4*)bdata;
    const int lbase = wave * ppw;
    const int gbase = g * chunk;

    __shared__ float  md[chunk];         // running min sq-dist (block-private)
    __shared__ float4 csh[D_ / 4];
    __shared__ float  red_v[WPB];
    __shared__ int    red_i[WPB];
    __shared__ int    s_ci;

    for (int i = threadIdx.x; i < chunk; i += T_) md[i] = 3.4e38f;

    for (int k = 0; k < K_; ++k) {
        // ---- this step's center index ----
        if (k == 0) {
            if (threadIdx.x == 0) s_ci = first_idx[b];
        } else if (wave == 0) {
            u64 pk = 0;
            if (lane < gpb) {
                const u64* slot = slots + (size_t)(k - 1) * SLOTS_PER_K
                                        + b * 32 + lane;
                do {
                    pk = __hip_atomic_load(slot, __ATOMIC_RELAXED,
                                           __HIP_MEMORY_SCOPE_AGENT);
                } while (pk == 0ULL);
            }
            #pragma unroll
            for (int m = 1; m < 64; m <<= 1) {
                u64 o = __shfl_xor(pk, m, 64);
                if (o > pk) pk = o;      // max packed == argmax w/ numpy ties
            }
            if (lane == 0) s_ci = (int)(~(unsigned)pk) & (N_ - 1);
        }
        __syncthreads();
        const int ci = s_ci;

        // ---- stage center row; block g==0 writes the output row ----
        if (threadIdx.x < D_ / 4)
            csh[threadIdx.x] = ((const float4*)(bdata + (size_t)ci * D_))[threadIdx.x];
        __syncthreads();
        if (g == 0 && threadIdx.x < D_ / 4)
            ((float4*)(centers + ((size_t)b * K_ + k) * D_))[threadIdx.x] = csh[threadIdx.x];
        if (k == K_ - 1) break;          // uniform exit

        // ---- min_d update + local argmax, depth-4 load pipeline ----
        const float4 c = csh[d4];
        float bv = -1.f; int bi = 0x7fffffff;
        float4 xb[4];
        #pragma unroll
        for (int t = 0; t < 4 && t < npass; ++t)
            xb[t] = rowp[(size_t)(gbase + lbase + t * 4 + sub) * 16 + d4];
        #pragma unroll 4
        for (int t = 0; t < npass; ++t) {
            float4 x = xb[t & 3];
            if (t + 4 < npass)
                xb[t & 3] = rowp[(size_t)(gbase + lbase + (t + 4) * 4 + sub) * 16 + d4];
            float dx = x.x - c.x, dy = x.y - c.y, dz = x.z - c.z, dw = x.w - c.w;
            float s = fmaf(dx, dx, fmaf(dy, dy, fmaf(dz, dz, dw * dw)));
            s += __shfl_xor(s, 1, 64);
            s += __shfl_xor(s, 2, 64);
            s += __shfl_xor(s, 4, 64);
            s += __shfl_xor(s, 8, 64);   // 16-lane sub-group holds d(p)
            const int lp = lbase + t * 4 + sub;
            float nv = fminf(md[lp], s);
            if (d4 == 0) md[lp] = nv;
            amax_comb(bv, bi, nv, gbase + lp);  // sub-group dups: harmless
        }
        #pragma unroll
        for (int m = 1; m < 64; m <<= 1) {
            float v2 = __shfl_xor(bv, m, 64);
            int   i2 = __shfl_xor(bi, m, 64);
            amax_comb(bv, bi, v2, i2);
        }
        if (lane == 0) { red_v[wave] = bv; red_i[wave] = bi; }
        __syncthreads();
        if (threadIdx.x == 0) {
            #pragma unroll
            for (int w = 1; w < WPB; ++w) amax_comb(bv, bi, red_v[w], red_i[w]);
            u64 pk = ((u64)__float_as_uint(bv) << 32) | (unsigned)(~bi);
            __hip_atomic_store(slots + (size_t)k * SLOTS_PER_K + b * 32 + g,
                               pk, __ATOMIC_RELAXED, __HIP_MEMORY_SCOPE_AGENT);
        }
        // no barrier: red_* reuse in step k+1 happens only after the
        // post-staging __syncthreads, which wave 0 crosses after reading red_*.
    }
}

// ------------------- round-1 multi-launch fallback path ---------------------
// Proven correct (absmax 0, 1827 us). Used only if coop occupancy < 2/CU.

#define FG   16
#define FPPT 4
#define FCHUNK (N_ / FG)

__device__ __forceinline__ void fb_block_argmax_store(
    float v, int i, int b, int g, int parity,
    float* __restrict__ pval, int* __restrict__ pidx,
    float* red_v, int* red_i)
{
    #pragma unroll
    for (int off = 32; off > 0; off >>= 1) {
        float v2 = __shfl_down(v, off, 64);
        int   i2 = __shfl_down(i, off, 64);
        amax_comb(v, i, v2, i2);
    }
    int lane = threadIdx.x & 63;
    int wave = threadIdx.x >> 6;
    if (lane == 0) { red_v[wave] = v; red_i[wave] = i; }
    __syncthreads();
    if (threadIdx.x == 0) {
        #pragma unroll
        for (int w = 1; w < T_ / 64; ++w) amax_comb(v, i, red_v[w], red_i[w]);
        pval[(b * 2 + parity) * FG + g] = v;
        pidx[(b * 2 + parity) * FG + g] = i;
    }
}

__device__ __forceinline__ float fb_dist2(const float4* __restrict__ row,
                                          const float4* csh)
{
    float ax = 0.f, ay = 0.f, az = 0.f, aw = 0.f;
    #pragma unroll
    for (int j = 0; j < D_ / 4; ++j) {
        float4 x = row[j];
        float4 c = csh[j];
        float dx = x.x - c.x, dy = x.y - c.y, dz = x.z - c.z, dw = x.w - c.w;
        ax = fmaf(dx, dx, ax);
        ay = fmaf(dy, dy, ay);
        az = fmaf(dz, dz, az);
        aw = fmaf(dw, dw, aw);
    }
    return (ax + ay) + (az + aw);
}

__global__ __launch_bounds__(T_) void kmpp_init(
    const float* __restrict__ data, const int* __restrict__ first_idx,
    float* __restrict__ min_d, float* __restrict__ pval, int* __restrict__ pidx,
    float* __restrict__ centers)
{
    const int blk = blockIdx.x;
    const int b = blk / FG, g = blk % FG;
    __shared__ float4 csh[D_ / 4];
    __shared__ float red_v[T_ / 64];
    __shared__ int   red_i[T_ / 64];

    const int ci = first_idx[b];
    const float4* crow = (const float4*)(data + ((size_t)b * N_ + ci) * D_);
    if (threadIdx.x < D_ / 4) csh[threadIdx.x] = crow[threadIdx.x];
    __syncthreads();
    if (g == 0 && threadIdx.x < D_ / 4)
        ((float4*)(centers + (size_t)b * K_ * D_))[threadIdx.x] = csh[threadIdx.x];

    float best_v = -1.f; int best_i = 0;
    for (int m = 0; m < FPPT; ++m) {
        const int p = g * FCHUNK + m * T_ + threadIdx.x;
        const float4* row = (const float4*)(data + ((size_t)b * N_ + p) * D_);
        float d = fb_dist2(row, csh);
        min_d[(size_t)b * N_ + p] = d;
        amax_comb(best_v, best_i, d, p);
    }
    fb_block_argmax_store(best_v, best_i, b, g, 0, pval, pidx, red_v, red_i);
}

__global__ __launch_bounds__(T_) void kmpp_step(
    const float* __restrict__ data, float* __restrict__ min_d,
    float* __restrict__ pval, int* __restrict__ pidx,
    float* __restrict__ centers, int k)
{
    const int blk = blockIdx.x;
    const int b = blk / FG, g = blk % FG;
    const int pin = (k - 1) & 1, pout = k & 1;
    __shared__ float4 csh[D_ / 4];
    __shared__ float red_v[T_ / 64];
    __shared__ int   red_i[T_ / 64];
    __shared__ int   sidx;

    if (threadIdx.x == 0) {
        float v = pval[(b * 2 + pin) * FG];
        int   i = pidx[(b * 2 + pin) * FG];
        for (int gg = 1; gg < FG; ++gg)
            amax_comb(v, i, pval[(b * 2 + pin) * FG + gg], pidx[(b * 2 + pin) * FG + gg]);
        sidx = i;
    }
    __syncthreads();
    const int ci = sidx;
    const float4* crow = (const float4*)(data + ((size_t)b * N_ + ci) * D_);
    if (threadIdx.x < D_ / 4) csh[threadIdx.x] = crow[threadIdx.x];
    __syncthreads();
    if (g == 0 && threadIdx.x < D_ / 4)
        ((float4*)(centers + ((size_t)b * K_ + k) * D_))[threadIdx.x] = csh[threadIdx.x];

    if (k == K_ - 1) return;

    float best_v = -1.f; int best_i = 0;
    for (int m = 0; m < FPPT; ++m) {
        const int p = g * FCHUNK + m * T_ + threadIdx.x;
        const float4* row = (const float4*)(data + ((size_t)b * N_ + p) * D_);
        float d = fb_dist2(row, csh);
        const size_t off = (size_t)b * N_ + p;
        float nv = fminf(min_d[off], d);
        min_d[off] = nv;
        amax_comb(best_v, best_i, nv, p);
    }
    fb_block_argmax_store(best_v, best_i, b, g, pout, pval, pidx, red_v, red_i);
}

// ---------------------------------------------------------------------------

extern "C" void kernel_launch(void* const* d_in, const int* in_sizes, int n_in,
                              void* d_out, int out_size, void* d_ws, size_t ws_size,
                              hipStream_t stream)
{
    const float* data      = (const float*)d_in[0];
    const int*   first_idx = (const int*)d_in[1];
    float*       centers   = (float*)d_out;

    // Exclusive ws layouts per path (never both used in one call):
    //   coop:     slots[K*B*32] u64 (512 KB)
    //   fallback: min_d[B*N] f32 | pval[B*2*FG] | pidx[B*2*FG]
    u64*   slots = (u64*)d_ws;
    float* min_d = (float*)d_ws;
    float* pval  = min_d + (size_t)B_ * N_;
    int*   pidx  = (int*)(pval + B_ * 2 * FG);

    // Capture-safe occupancy queries (pure host, deterministic).
    int occ5 = 0, occ4 = 0;
    (void)hipOccupancyMaxActiveBlocksPerMultiprocessor(&occ5, kmpp_coop<5>, T_, 0);
    (void)hipOccupancyMaxActiveBlocksPerMultiprocessor(&occ4, kmpp_coop<4>, T_, 0);

    const void* kfn = nullptr;
    int gshift = 0;
    if (occ5 >= 4)      { kfn = (const void*)kmpp_coop<5>; gshift = 5; } // 1024 blk
    else if (occ4 >= 2) { kfn = (const void*)kmpp_coop<4>; gshift = 4; } // 512 blk

    if (kfn) {
        const int nslots = K_ * SLOTS_PER_K;
        hipLaunchKernelGGL(kmpp_zero_slots, dim3((nslots + T_ - 1) / T_), dim3(T_),
                           0, stream, slots, nslots);
        void* args[] = { (void*)&data, (void*)&first_idx,
                         (void*)&slots, (void*)&centers };
        hipError_t err = hipLaunchCooperativeKernel(
            kfn, dim3(B_ << gshift), dim3(T_), args, 0, stream);
        if (err == hipSuccess) return;
        (void)hipGetLastError();   // clear sticky error, fall through
    }

    // Fallback: proven multi-launch path.
    dim3 grid(B_ * FG), block(T_);
    hipLaunchKernelGGL(kmpp_init, grid, block, 0, stream,
                       data, first_idx, min_d, pval, pidx, centers);
    for (int k = 1; k < K_; ++k) {
        hipLaunchKernelGGL(kmpp_step, grid, block, 0, stream,
                           data, min_d, pval, pidx, centers, k);
    }
}